// Round 12
// baseline (1096.806 us; speedup 1.0000x reference)
//
#include <hip/hip_runtime.h>
#include <hip/hip_bf16.h>

// DynamicBlockSparseMoE: top-4-of-16 expert block-sparse MoE.
// memset colsum -> cvt+colsum(atomic) -> gate top4 -> merged gather(w,agg) ->
// GEMM1 -> GEMM2(+bias). GEMMs: 256x256 WG-tile, BK=64, **4 waves** of 128x128
// (cuts per-CU LDS fragment traffic 192->128KB/tile), 2 phases/K-tile,
// acc[8][8] (256 VGPR), unpinned schedule, XOR-swizzled LDS, 2D XCD map.

#define BATCH 4096
#define DIN 4096
#define NE 16
#define HD 1024
#define TOPK 4
#define TOTC (NE * HD)
#define NT 64

using bf16 = __hip_bfloat16;
typedef __attribute__((ext_vector_type(8))) short short8;
typedef __attribute__((ext_vector_type(4))) float f32x4;

__device__ inline short f2bs(float f) {
  __hip_bfloat16 h = __float2bfloat16(f);
  return *reinterpret_cast<short*>(&h);
}

// ---- fused bf16 convert + column-sum (atomic) ------------------------------
__global__ void k_cvtsum(const float* __restrict__ x, bf16* __restrict__ xb,
                         float* __restrict__ colsum) {
  const int t = threadIdx.x;
  const int lane = t & 63;
  const int w = t >> 6;  // 0..3
  const int c = blockIdx.x * 256 + lane * 4;
  const int r0 = blockIdx.y * 128 + w * 32;
  float4 s = {0.f, 0.f, 0.f, 0.f};
  for (int i = 0; i < 32; ++i) {
    size_t off = (size_t)(r0 + i) * DIN + c;
    float4 v = *reinterpret_cast<const float4*>(x + off);
    s.x += v.x; s.y += v.y; s.z += v.z; s.w += v.w;
    ushort4 b;
    b.x = (unsigned short)f2bs(v.x); b.y = (unsigned short)f2bs(v.y);
    b.z = (unsigned short)f2bs(v.z); b.w = (unsigned short)f2bs(v.w);
    *reinterpret_cast<ushort4*>(reinterpret_cast<char*>(xb) + off * 2) = b;
  }
  __shared__ float sm[4][256];
  sm[w][lane * 4 + 0] = s.x; sm[w][lane * 4 + 1] = s.y;
  sm[w][lane * 4 + 2] = s.z; sm[w][lane * 4 + 3] = s.w;
  __syncthreads();
  float tot = sm[0][t] + sm[1][t] + sm[2][t] + sm[3][t];
  atomicAdd(&colsum[blockIdx.x * 256 + t], tot);
}

__global__ void k_gate(const float* __restrict__ colsum, const float* __restrict__ gw,
                       const float* __restrict__ gb, int* __restrict__ ids) {
  __shared__ float red[4][16];
  __shared__ float gs[16];
  int t = threadIdx.x;
  int e = t & 15, kg = t >> 4;
  float p = 0.f;
  for (int k = kg; k < DIN; k += 16) p += colsum[k] * gw[(size_t)k * NE + e];
  p += __shfl_down(p, 32);
  p += __shfl_down(p, 16);
  if ((t & 63) < 16) red[t >> 6][e] = p;
  __syncthreads();
  if (t < 16) gs[t] = red[0][t] + red[1][t] + red[2][t] + red[3][t] + (float)BATCH * gb[t];
  __syncthreads();
  if (t == 0) {
    float v[16];
    #pragma unroll
    for (int i = 0; i < 16; ++i) v[i] = gs[i];
    for (int j = 0; j < TOPK; ++j) {
      int bi = 0;
      float bv = v[0];
      for (int i2 = 1; i2 < 16; ++i2)
        if (v[i2] > bv) { bv = v[i2]; bi = i2; }
      ids[j] = bi;
      v[bi] = -3.4e38f;
    }
  }
}

// ---- merged gather: 8192 tiles (0-4095 = weight, 4096-8191 = agg_w) --------
__global__ void k_gather(const float* __restrict__ w, const float* __restrict__ a,
                         const int* __restrict__ ids,
                         bf16* __restrict__ wbt, bf16* __restrict__ abt) {
  __shared__ float tile[64 * 65];
  const int t = threadIdx.x;
  const int tc = t & 15, kr = t >> 4;
  const int tk = t & 7, nr0 = t >> 3;
  for (int tl = blockIdx.x; tl < 8192; tl += 2048) {
    const int wsel = tl < 4096;
    const int tidx = wsel ? tl : tl - 4096;
    const int k0 = (tidx & 63) * 64, n0 = (tidx >> 6) * 64;
    if (wsel) {
      const int e = ids[n0 >> 10];
      const int wc0 = e * HD + (n0 & 1023);
      #pragma unroll
      for (int j = 0; j < 4; ++j) {
        int kk = kr + j * 16;
        float4 v = *reinterpret_cast<const float4*>(w + (size_t)(k0 + kk) * TOTC + wc0 + tc * 4);
        float* dst = &tile[kk * 65 + tc * 4];
        dst[0] = v.x; dst[1] = v.y; dst[2] = v.z; dst[3] = v.w;
      }
    } else {
      const int e = ids[k0 >> 10];
      const int ar0 = e * HD + (k0 & 1023);
      #pragma unroll
      for (int j = 0; j < 4; ++j) {
        int kk = kr + j * 16;
        float4 v = *reinterpret_cast<const float4*>(a + (size_t)(ar0 + kk) * 4096 + n0 + tc * 4);
        float* dst = &tile[kk * 65 + tc * 4];
        dst[0] = v.x; dst[1] = v.y; dst[2] = v.z; dst[3] = v.w;
      }
    }
    __syncthreads();
    bf16* dstp = wsel ? wbt : abt;
    #pragma unroll
    for (int i = 0; i < 2; ++i) {
      int n = n0 + nr0 + i * 32;
      short8 r;
      #pragma unroll
      for (int m = 0; m < 8; ++m) r[m] = f2bs(tile[(tk * 8 + m) * 65 + nr0 + i * 32]);
      *reinterpret_cast<short8*>(dstp + (size_t)n * DIN + k0 + tk * 8) = r;
    }
    __syncthreads();
  }
}

// ---- GEMM: 256x256 WG-tile, 4 waves of 128x128, BK=64, 2 phases/K-tile -----
#define MFMA_BF16 __builtin_amdgcn_mfma_f32_16x16x32_bf16
#define VM0 asm volatile("s_waitcnt vmcnt(0)" ::: "memory")
#define NOST ((void)0)

// One phase = one kk half: 8 B-frags + 8 A-frags (16 ds_read_b128/wave),
// 64 MFMA. STG = 8 global_load_lds. Unpinned (compiler interleaves).
#define PH(BUF, KK, STG, GATE)                                                  \
  do {                                                                          \
    short8 bfr[8];                                                              \
    _Pragma("unroll") for (int nf = 0; nf < 8; ++nf) bfr[nf] = LDB(BUF, nf, KK); \
    STG;                                                                        \
    GATE;                                                                       \
    __builtin_amdgcn_s_barrier();                                               \
    __builtin_amdgcn_s_setprio(1);                                              \
    _Pragma("unroll") for (int m = 0; m < 8; ++m) {                             \
      short8 afr = LDA(BUF, m, KK);                                             \
      _Pragma("unroll") for (int nf = 0; nf < 8; ++nf)                          \
        acc[m][nf] = MFMA_BF16(afr, bfr[nf], acc[m][nf], 0, 0, 0);              \
    }                                                                           \
    __builtin_amdgcn_s_setprio(0);                                              \
    __builtin_amdgcn_s_barrier();                                               \
  } while (0)

template <int STORE_F32>
__global__ __launch_bounds__(256, 1) void k_gemm4(
    const bf16* __restrict__ A, const bf16* __restrict__ Bt,
    bf16* __restrict__ Cb, float* __restrict__ Cf, const float* __restrict__ bias) {
  __shared__ __align__(16) char smraw[131072];  // dbuf x (A 32KB | B 32KB)
  const int t = threadIdx.x;
  const int lane = t & 63;
  const int w = t >> 6;      // 0..3
  const int wr = w >> 1;     // 0..1 (128-row half)
  const int wc = w & 1;      // 0..1 (128-col half)

  const int bid = blockIdx.x;
  const int xcd = bid & 7;
  const int i = bid >> 3;
  const int bm = ((xcd >> 1) * 4 + (i & 3)) * 256;
  const int bn = ((xcd & 1) * 8 + (i >> 2)) * 256;

  f32x4 acc[8][8] = {};  // 128x128 per wave: 8x8 16x16 frags (256 VGPR)

  // staging: 256 thr, 8 rounds of 32 rows x 8 granules (4KB/round)
  const int sr = t >> 3;      // 0..31
  const int sg = t & 7;       // granule

  auto STAGE_A = [&](int buf, int kt) {
    #pragma unroll
    for (int i2 = 0; i2 < 8; ++i2) {
      int r = sr + i2 * 32;
      const bf16* g = A + (size_t)(bm + r) * 4096 + kt * 64 + ((sg ^ (r & 7)) * 8);
      __builtin_amdgcn_global_load_lds(
          (const __attribute__((address_space(1))) void*)g,
          (__attribute__((address_space(3))) void*)(smraw + buf * 65536 + r * 128 + sg * 16),
          16, 0, 0);
    }
  };
  auto STAGE_B = [&](int buf, int kt) {
    #pragma unroll
    for (int i2 = 0; i2 < 8; ++i2) {
      int r = sr + i2 * 32;
      const bf16* g = Bt + (size_t)(bn + r) * 4096 + kt * 64 + ((sg ^ (r & 7)) * 8);
      __builtin_amdgcn_global_load_lds(
          (const __attribute__((address_space(1))) void*)g,
          (__attribute__((address_space(3))) void*)(smraw + buf * 65536 + 32768 + r * 128 + sg * 16),
          16, 0, 0);
    }
  };
  auto LDA = [&](int buf, int mf, int kk) -> short8 {
    int r = wr * 128 + mf * 16 + (lane & 15);
    int g = ((kk * 4 + (lane >> 4)) ^ (r & 7)) * 16;
    return *reinterpret_cast<const short8*>(smraw + buf * 65536 + r * 128 + g);
  };
  auto LDB = [&](int buf, int nf, int kk) -> short8 {
    int r = wc * 128 + nf * 16 + (lane & 15);
    int g = ((kk * 4 + (lane >> 4)) ^ (r & 7)) * 16;
    return *reinterpret_cast<const short8*>(smraw + buf * 65536 + 32768 + r * 128 + g);
  };

  // Prologue: stage tile 0 into buf0, drain.
  STAGE_A(0, 0);
  STAGE_B(0, 0);
  VM0;
  __builtin_amdgcn_s_barrier();

  // Steady: tile j from buf j&1; stage A(j+1) in PH0, B(j+1) in PH1 into
  // buf (j+1)&1; gate VM0 at PH1 (loads had ~1 phase + barrier to land).
  for (int j = 0; j < NT - 1; ++j) {
    const int cur = j & 1, nxt = cur ^ 1;
    PH(cur, 0, STAGE_A(nxt, j + 1), NOST);
    PH(cur, 1, STAGE_B(nxt, j + 1), VM0);
  }
  PH((NT - 1) & 1, 0, NOST, NOST);
  PH((NT - 1) & 1, 1, NOST, NOST);

  // Epilogue
  const int cr = (lane >> 4) * 4;
  const int cc = lane & 15;
  #pragma unroll
  for (int mf = 0; mf < 8; ++mf) {
    #pragma unroll
    for (int nf = 0; nf < 8; ++nf) {
      int row = bm + wr * 128 + mf * 16 + cr;
      int col = bn + wc * 128 + nf * 16 + cc;
      #pragma unroll
      for (int r = 0; r < 4; ++r) {
        if constexpr (STORE_F32) {
          Cf[(size_t)(row + r) * 4096 + col] = acc[mf][nf][r] + bias[col];
        } else {
          Cb[(size_t)(row + r) * 4096 + col] = __float2bfloat16(acc[mf][nf][r]);
        }
      }
    }
  }
}

// ---- launch ----------------------------------------------------------------
extern "C" void kernel_launch(void* const* d_in, const int* in_sizes, int n_in,
                              void* d_out, int out_size, void* d_ws, size_t ws_size,
                              hipStream_t stream) {
  const float* x = (const float*)d_in[0];
  const float* gate_w = (const float*)d_in[1];
  const float* gate_b = (const float*)d_in[2];
  const float* weight = (const float*)d_in[3];
  const float* agg_w = (const float*)d_in[4];
  const float* agg_b = (const float*)d_in[5];
  float* out = (float*)d_out;
  char* ws = (char*)d_ws;

  // ws: colsum 16KB @0 | ids @16KB | mid 32MB @4MB | abt 32MB @36MB
  float* colsum = (float*)ws;
  int* ids = (int*)(ws + 16384);
  bf16* mid = (bf16*)(ws + (4u << 20));
  bf16* abt = (bf16*)(ws + (36u << 20));
  // scratch inside d_out (dead before GEMM2 writes it):
  bf16* xb = (bf16*)d_out;
  bf16* wbt = (bf16*)((char*)d_out + (32u << 20));

  hipMemsetAsync(colsum, 0, DIN * sizeof(float), stream);
  k_cvtsum<<<dim3(16, 32), 256, 0, stream>>>(x, xb, colsum);
  k_gate<<<1, 256, 0, stream>>>(colsum, gate_w, gate_b, ids);
  k_gather<<<2048, 256, 0, stream>>>(weight, agg_w, ids, wbt, abt);
  k_gemm4<0><<<256, 256, 0, stream>>>(xb, wbt, mid, nullptr, nullptr);
  k_gemm4<1><<<256, 256, 0, stream>>>(mid, abt, nullptr, out, agg_b);
}

// Round 13
// 374.544 us; speedup vs baseline: 2.9284x; 2.9284x over previous
//
#include <hip/hip_runtime.h>
#include <hip/hip_bf16.h>

// DynamicBlockSparseMoE: top-4-of-16 expert block-sparse MoE.
// memset colsum -> cvt+colsum(atomic) -> gate top4 -> merged gather(w,agg) ->
// GEMM1 -> GEMM2(+bias). GEMMs: 256x256, BK=64, 8 waves, 16x16x32 MFMA,
// 4 phases/K-tile with ONE barrier per phase (reads+stage | barrier | MFMA),
// no setprio (m190: hurts non-8-phase structures), counted vmcnt, 2D XCD map.

#define BATCH 4096
#define DIN 4096
#define NE 16
#define HD 1024
#define TOPK 4
#define TOTC (NE * HD)
#define NT 64

using bf16 = __hip_bfloat16;
typedef __attribute__((ext_vector_type(8))) short short8;
typedef __attribute__((ext_vector_type(4))) float f32x4;

__device__ inline short f2bs(float f) {
  __hip_bfloat16 h = __float2bfloat16(f);
  return *reinterpret_cast<short*>(&h);
}

// ---- fused bf16 convert + column-sum (atomic) ------------------------------
__global__ void k_cvtsum(const float* __restrict__ x, bf16* __restrict__ xb,
                         float* __restrict__ colsum) {
  const int t = threadIdx.x;
  const int lane = t & 63;
  const int w = t >> 6;  // 0..3
  const int c = blockIdx.x * 256 + lane * 4;
  const int r0 = blockIdx.y * 128 + w * 32;
  float4 s = {0.f, 0.f, 0.f, 0.f};
  for (int i = 0; i < 32; ++i) {
    size_t off = (size_t)(r0 + i) * DIN + c;
    float4 v = *reinterpret_cast<const float4*>(x + off);
    s.x += v.x; s.y += v.y; s.z += v.z; s.w += v.w;
    ushort4 b;
    b.x = (unsigned short)f2bs(v.x); b.y = (unsigned short)f2bs(v.y);
    b.z = (unsigned short)f2bs(v.z); b.w = (unsigned short)f2bs(v.w);
    *reinterpret_cast<ushort4*>(reinterpret_cast<char*>(xb) + off * 2) = b;
  }
  __shared__ float sm[4][256];
  sm[w][lane * 4 + 0] = s.x; sm[w][lane * 4 + 1] = s.y;
  sm[w][lane * 4 + 2] = s.z; sm[w][lane * 4 + 3] = s.w;
  __syncthreads();
  float tot = sm[0][t] + sm[1][t] + sm[2][t] + sm[3][t];
  atomicAdd(&colsum[blockIdx.x * 256 + t], tot);
}

__global__ void k_gate(const float* __restrict__ colsum, const float* __restrict__ gw,
                       const float* __restrict__ gb, int* __restrict__ ids) {
  __shared__ float red[4][16];
  __shared__ float gs[16];
  int t = threadIdx.x;
  int e = t & 15, kg = t >> 4;
  float p = 0.f;
  for (int k = kg; k < DIN; k += 16) p += colsum[k] * gw[(size_t)k * NE + e];
  p += __shfl_down(p, 32);
  p += __shfl_down(p, 16);
  if ((t & 63) < 16) red[t >> 6][e] = p;
  __syncthreads();
  if (t < 16) gs[t] = red[0][t] + red[1][t] + red[2][t] + red[3][t] + (float)BATCH * gb[t];
  __syncthreads();
  if (t == 0) {
    float v[16];
    #pragma unroll
    for (int i = 0; i < 16; ++i) v[i] = gs[i];
    for (int j = 0; j < TOPK; ++j) {
      int bi = 0;
      float bv = v[0];
      for (int i2 = 1; i2 < 16; ++i2)
        if (v[i2] > bv) { bv = v[i2]; bi = i2; }
      ids[j] = bi;
      v[bi] = -3.4e38f;
    }
  }
}

// ---- merged gather: 8192 tiles (0-4095 = weight, 4096-8191 = agg_w) --------
__global__ void k_gather(const float* __restrict__ w, const float* __restrict__ a,
                         const int* __restrict__ ids,
                         bf16* __restrict__ wbt, bf16* __restrict__ abt) {
  __shared__ float tile[64 * 65];
  const int t = threadIdx.x;
  const int tc = t & 15, kr = t >> 4;
  const int tk = t & 7, nr0 = t >> 3;
  for (int tl = blockIdx.x; tl < 8192; tl += 2048) {
    const int wsel = tl < 4096;
    const int tidx = wsel ? tl : tl - 4096;
    const int k0 = (tidx & 63) * 64, n0 = (tidx >> 6) * 64;
    if (wsel) {
      const int e = ids[n0 >> 10];
      const int wc0 = e * HD + (n0 & 1023);
      #pragma unroll
      for (int j = 0; j < 4; ++j) {
        int kk = kr + j * 16;
        float4 v = *reinterpret_cast<const float4*>(w + (size_t)(k0 + kk) * TOTC + wc0 + tc * 4);
        float* dst = &tile[kk * 65 + tc * 4];
        dst[0] = v.x; dst[1] = v.y; dst[2] = v.z; dst[3] = v.w;
      }
    } else {
      const int e = ids[k0 >> 10];
      const int ar0 = e * HD + (k0 & 1023);
      #pragma unroll
      for (int j = 0; j < 4; ++j) {
        int kk = kr + j * 16;
        float4 v = *reinterpret_cast<const float4*>(a + (size_t)(ar0 + kk) * 4096 + n0 + tc * 4);
        float* dst = &tile[kk * 65 + tc * 4];
        dst[0] = v.x; dst[1] = v.y; dst[2] = v.z; dst[3] = v.w;
      }
    }
    __syncthreads();
    bf16* dstp = wsel ? wbt : abt;
    #pragma unroll
    for (int i = 0; i < 2; ++i) {
      int n = n0 + nr0 + i * 32;
      short8 r;
      #pragma unroll
      for (int m = 0; m < 8; ++m) r[m] = f2bs(tile[(tk * 8 + m) * 65 + nr0 + i * 32]);
      *reinterpret_cast<short8*>(dstp + (size_t)n * DIN + k0 + tk * 8) = r;
    }
    __syncthreads();
  }
}

// ---- GEMM: 256x256, BK=64, 8 waves, 4 phases/K-tile, 1 barrier/phase -------
#define MFMA_BF16 __builtin_amdgcn_mfma_f32_16x16x32_bf16
#define VM4 asm volatile("s_waitcnt vmcnt(4)" ::: "memory")
#define VM0 asm volatile("s_waitcnt vmcnt(0)" ::: "memory")
#define NOST ((void)0)

// Phase: {ds_reads; STG; GATE} -> s_barrier -> MFMA. Single barrier per phase:
// safe because any wave's earliest conflicting stage-write (issued 2 phases
// after the slot's last read) implies all waves' consuming lgkm waits passed.
#define PH(BUF, Q, STG, GATE)                                                   \
  do {                                                                          \
    if ((Q) == 0) {                                                             \
      _Pragma("unroll") for (int nf = 0; nf < 4; ++nf) {                        \
        bfrag[nf][0] = LDB(BUF, nf, 0);                                         \
        bfrag[nf][1] = LDB(BUF, nf, 1);                                         \
      }                                                                         \
    }                                                                           \
    short8 aA0 = LDA(BUF, 2 * (Q), 0), aA1 = LDA(BUF, 2 * (Q), 1);              \
    short8 aB0 = LDA(BUF, 2 * (Q) + 1, 0), aB1 = LDA(BUF, 2 * (Q) + 1, 1);      \
    STG;                                                                        \
    GATE;                                                                       \
    __builtin_amdgcn_s_barrier();                                               \
    _Pragma("unroll") for (int nf = 0; nf < 4; ++nf) {                          \
      acc[2 * (Q)][nf] = MFMA_BF16(aA0, bfrag[nf][0], acc[2 * (Q)][nf], 0, 0, 0);       \
      acc[2 * (Q)][nf] = MFMA_BF16(aA1, bfrag[nf][1], acc[2 * (Q)][nf], 0, 0, 0);       \
      acc[2 * (Q) + 1][nf] = MFMA_BF16(aB0, bfrag[nf][0], acc[2 * (Q) + 1][nf], 0, 0, 0); \
      acc[2 * (Q) + 1][nf] = MFMA_BF16(aB1, bfrag[nf][1], acc[2 * (Q) + 1][nf], 0, 0, 0); \
    }                                                                           \
  } while (0)

template <int STORE_F32>
__global__ __launch_bounds__(512, 2) void k_gemm8(
    const bf16* __restrict__ A, const bf16* __restrict__ Bt,
    bf16* __restrict__ Cb, float* __restrict__ Cf, const float* __restrict__ bias) {
  __shared__ __align__(16) char smraw[131072];
  const int t = threadIdx.x;
  const int lane = t & 63;
  const int w = t >> 6;
  const int wr = w >> 2;
  const int wc = w & 3;

  const int bid = blockIdx.x;
  const int xcd = bid & 7;
  const int i = bid >> 3;
  const int bm = ((xcd >> 1) * 4 + (i & 3)) * 256;
  const int bn = ((xcd & 1) * 8 + (i >> 2)) * 256;

  f32x4 acc[8][4] = {};
  short8 bfrag[4][2];

  const int srow = w * 16 + (lane >> 3);
  const int sgr = lane & 7;

  auto STAGE_A = [&](int buf, int half, int kt) {
    char* lb = smraw + buf * 65536 + half * 16384 + w * 2048 + lane * 16;
    #pragma unroll
    for (int i2 = 0; i2 < 2; ++i2) {
      int r = srow + i2 * 8;
      const bf16* g = A + (size_t)(bm + half * 128 + r) * 4096 + kt * 64 + ((sgr ^ (r & 7)) * 8);
      __builtin_amdgcn_global_load_lds(
          (const __attribute__((address_space(1))) void*)g,
          (__attribute__((address_space(3))) void*)(lb + i2 * 1024), 16, 0, 0);
    }
  };
  auto STAGE_B = [&](int buf, int half, int kt) {
    char* lb = smraw + buf * 65536 + 32768 + half * 16384 + w * 2048 + lane * 16;
    #pragma unroll
    for (int i2 = 0; i2 < 2; ++i2) {
      int r = srow + i2 * 8;
      const bf16* g = Bt + (size_t)(bn + half * 128 + r) * 4096 + kt * 64 + ((sgr ^ (r & 7)) * 8);
      __builtin_amdgcn_global_load_lds(
          (const __attribute__((address_space(1))) void*)g,
          (__attribute__((address_space(3))) void*)(lb + i2 * 1024), 16, 0, 0);
    }
  };
  auto LDA = [&](int buf, int mf, int kk) -> short8 {
    int r = mf * 16 + (lane & 15);
    int kb = ((kk * 4 + (lane >> 4)) ^ (r & 7)) * 16;
    return *reinterpret_cast<const short8*>(smraw + buf * 65536 + wr * 16384 + r * 128 + kb);
  };
  auto LDB = [&](int buf, int nf, int kk) -> short8 {
    int nc = wc * 64 + nf * 16 + (lane & 15);
    int half = nc >> 7, r = nc & 127;
    int kb = ((kk * 4 + (lane >> 4)) ^ (r & 7)) * 16;
    return *reinterpret_cast<const short8*>(smraw + buf * 65536 + 32768 + half * 16384 + r * 128 + kb);
  };

  // Prologue: B(0), A(0) -> buf0; B(1) -> buf1. Complete oldest 8 (B0,A0).
  STAGE_B(0, 0, 0); STAGE_B(0, 1, 0);
  STAGE_A(0, 0, 0); STAGE_A(0, 1, 0);
  STAGE_B(1, 0, 1); STAGE_B(1, 1, 1);
  VM4;
  __builtin_amdgcn_s_barrier();

  // Steady: tiles a=2t (buf0), a+1 (buf1); stages A(a+1), B(a+2), A(a+2), B(a+3).
  for (int tt = 0; tt < 31; ++tt) {
    const int a = 2 * tt;
    PH(0, 0, STAGE_A(1, 0, a + 1), NOST);
    PH(0, 1, STAGE_A(1, 1, a + 1), NOST);
    PH(0, 2, STAGE_B(0, 0, a + 2), NOST);
    PH(0, 3, STAGE_B(0, 1, a + 2), VM4);
    PH(1, 0, STAGE_A(0, 0, a + 2), NOST);
    PH(1, 1, STAGE_A(0, 1, a + 2), NOST);
    PH(1, 2, STAGE_B(1, 0, a + 3), NOST);
    PH(1, 3, STAGE_B(1, 1, a + 3), VM4);
  }
  // Tail: tiles 62 (buf0), 63 (buf1). A(63) staged in ph0-1, then drain.
  PH(0, 0, STAGE_A(1, 0, 63), NOST);
  PH(0, 1, STAGE_A(1, 1, 63), NOST);
  PH(0, 2, NOST, NOST);
  PH(0, 3, NOST, VM0);
  PH(1, 0, NOST, NOST);
  PH(1, 1, NOST, NOST);
  PH(1, 2, NOST, NOST);
  PH(1, 3, NOST, NOST);

  const int cr = (lane >> 4) * 4;
  const int cc = lane & 15;
  #pragma unroll
  for (int mf = 0; mf < 8; ++mf) {
    #pragma unroll
    for (int nf = 0; nf < 4; ++nf) {
      int row = bm + wr * 128 + mf * 16 + cr;
      int col = bn + wc * 64 + nf * 16 + cc;
      #pragma unroll
      for (int r = 0; r < 4; ++r) {
        if constexpr (STORE_F32) {
          Cf[(size_t)(row + r) * 4096 + col] = acc[mf][nf][r] + bias[col];
        } else {
          Cb[(size_t)(row + r) * 4096 + col] = __float2bfloat16(acc[mf][nf][r]);
        }
      }
    }
  }
}

// ---- launch ----------------------------------------------------------------
extern "C" void kernel_launch(void* const* d_in, const int* in_sizes, int n_in,
                              void* d_out, int out_size, void* d_ws, size_t ws_size,
                              hipStream_t stream) {
  const float* x = (const float*)d_in[0];
  const float* gate_w = (const float*)d_in[1];
  const float* gate_b = (const float*)d_in[2];
  const float* weight = (const float*)d_in[3];
  const float* agg_w = (const float*)d_in[4];
  const float* agg_b = (const float*)d_in[5];
  float* out = (float*)d_out;
  char* ws = (char*)d_ws;

  // ws: colsum 16KB @0 | ids @16KB | mid 32MB @4MB | abt 32MB @36MB
  float* colsum = (float*)ws;
  int* ids = (int*)(ws + 16384);
  bf16* mid = (bf16*)(ws + (4u << 20));
  bf16* abt = (bf16*)(ws + (36u << 20));
  // scratch inside d_out (dead before GEMM2 writes it):
  bf16* xb = (bf16*)d_out;
  bf16* wbt = (bf16*)((char*)d_out + (32u << 20));

  hipMemsetAsync(colsum, 0, DIN * sizeof(float), stream);
  k_cvtsum<<<dim3(16, 32), 256, 0, stream>>>(x, xb, colsum);
  k_gate<<<1, 256, 0, stream>>>(colsum, gate_w, gate_b, ids);
  k_gather<<<2048, 256, 0, stream>>>(weight, agg_w, ids, wbt, abt);
  k_gemm8<0><<<256, 512, 0, stream>>>(xb, wbt, mid, nullptr, nullptr);
  k_gemm8<1><<<256, 512, 0, stream>>>(mid, abt, nullptr, out, agg_b);
}

// Round 14
// 373.378 us; speedup vs baseline: 2.9375x; 1.0031x over previous
//
#include <hip/hip_runtime.h>
#include <hip/hip_bf16.h>

// DynamicBlockSparseMoE: top-4-of-16 expert block-sparse MoE.
// memset colsum -> cvt+colsum(atomic) -> gate top4 -> merged gather(w,agg) ->
// GEMM1 -> GEMM2(+bias). GEMMs: 256x256, BK=64, 8 waves, 16x16x32 MFMA,
// 2 phases/K-tile, ONE barrier per phase (reads+stage | barrier | 32 MFMA),
// counted vmcnt(4), no setprio/pins, 2D XCD map.

#define BATCH 4096
#define DIN 4096
#define NE 16
#define HD 1024
#define TOPK 4
#define TOTC (NE * HD)
#define NT 64

using bf16 = __hip_bfloat16;
typedef __attribute__((ext_vector_type(8))) short short8;
typedef __attribute__((ext_vector_type(4))) float f32x4;

__device__ inline short f2bs(float f) {
  __hip_bfloat16 h = __float2bfloat16(f);
  return *reinterpret_cast<short*>(&h);
}

// ---- fused bf16 convert + column-sum (atomic) ------------------------------
__global__ void k_cvtsum(const float* __restrict__ x, bf16* __restrict__ xb,
                         float* __restrict__ colsum) {
  const int t = threadIdx.x;
  const int lane = t & 63;
  const int w = t >> 6;  // 0..3
  const int c = blockIdx.x * 256 + lane * 4;
  const int r0 = blockIdx.y * 128 + w * 32;
  float4 s = {0.f, 0.f, 0.f, 0.f};
  for (int i = 0; i < 32; ++i) {
    size_t off = (size_t)(r0 + i) * DIN + c;
    float4 v = *reinterpret_cast<const float4*>(x + off);
    s.x += v.x; s.y += v.y; s.z += v.z; s.w += v.w;
    ushort4 b;
    b.x = (unsigned short)f2bs(v.x); b.y = (unsigned short)f2bs(v.y);
    b.z = (unsigned short)f2bs(v.z); b.w = (unsigned short)f2bs(v.w);
    *reinterpret_cast<ushort4*>(reinterpret_cast<char*>(xb) + off * 2) = b;
  }
  __shared__ float sm[4][256];
  sm[w][lane * 4 + 0] = s.x; sm[w][lane * 4 + 1] = s.y;
  sm[w][lane * 4 + 2] = s.z; sm[w][lane * 4 + 3] = s.w;
  __syncthreads();
  float tot = sm[0][t] + sm[1][t] + sm[2][t] + sm[3][t];
  atomicAdd(&colsum[blockIdx.x * 256 + t], tot);
}

__global__ void k_gate(const float* __restrict__ colsum, const float* __restrict__ gw,
                       const float* __restrict__ gb, int* __restrict__ ids) {
  __shared__ float red[4][16];
  __shared__ float gs[16];
  int t = threadIdx.x;
  int e = t & 15, kg = t >> 4;
  float p = 0.f;
  for (int k = kg; k < DIN; k += 16) p += colsum[k] * gw[(size_t)k * NE + e];
  p += __shfl_down(p, 32);
  p += __shfl_down(p, 16);
  if ((t & 63) < 16) red[t >> 6][e] = p;
  __syncthreads();
  if (t < 16) gs[t] = red[0][t] + red[1][t] + red[2][t] + red[3][t] + (float)BATCH * gb[t];
  __syncthreads();
  if (t == 0) {
    float v[16];
    #pragma unroll
    for (int i = 0; i < 16; ++i) v[i] = gs[i];
    for (int j = 0; j < TOPK; ++j) {
      int bi = 0;
      float bv = v[0];
      for (int i2 = 1; i2 < 16; ++i2)
        if (v[i2] > bv) { bv = v[i2]; bi = i2; }
      ids[j] = bi;
      v[bi] = -3.4e38f;
    }
  }
}

// ---- merged gather: 8192 tiles (0-4095 = weight, 4096-8191 = agg_w) --------
__global__ void k_gather(const float* __restrict__ w, const float* __restrict__ a,
                         const int* __restrict__ ids,
                         bf16* __restrict__ wbt, bf16* __restrict__ abt) {
  __shared__ float tile[64 * 65];
  const int t = threadIdx.x;
  const int tc = t & 15, kr = t >> 4;
  const int tk = t & 7, nr0 = t >> 3;
  for (int tl = blockIdx.x; tl < 8192; tl += 2048) {
    const int wsel = tl < 4096;
    const int tidx = wsel ? tl : tl - 4096;
    const int k0 = (tidx & 63) * 64, n0 = (tidx >> 6) * 64;
    if (wsel) {
      const int e = ids[n0 >> 10];
      const int wc0 = e * HD + (n0 & 1023);
      #pragma unroll
      for (int j = 0; j < 4; ++j) {
        int kk = kr + j * 16;
        float4 v = *reinterpret_cast<const float4*>(w + (size_t)(k0 + kk) * TOTC + wc0 + tc * 4);
        float* dst = &tile[kk * 65 + tc * 4];
        dst[0] = v.x; dst[1] = v.y; dst[2] = v.z; dst[3] = v.w;
      }
    } else {
      const int e = ids[k0 >> 10];
      const int ar0 = e * HD + (k0 & 1023);
      #pragma unroll
      for (int j = 0; j < 4; ++j) {
        int kk = kr + j * 16;
        float4 v = *reinterpret_cast<const float4*>(a + (size_t)(ar0 + kk) * 4096 + n0 + tc * 4);
        float* dst = &tile[kk * 65 + tc * 4];
        dst[0] = v.x; dst[1] = v.y; dst[2] = v.z; dst[3] = v.w;
      }
    }
    __syncthreads();
    bf16* dstp = wsel ? wbt : abt;
    #pragma unroll
    for (int i = 0; i < 2; ++i) {
      int n = n0 + nr0 + i * 32;
      short8 r;
      #pragma unroll
      for (int m = 0; m < 8; ++m) r[m] = f2bs(tile[(tk * 8 + m) * 65 + nr0 + i * 32]);
      *reinterpret_cast<short8*>(dstp + (size_t)n * DIN + k0 + tk * 8) = r;
    }
    __syncthreads();
  }
}

// ---- GEMM: 256x256, BK=64, 8 waves, 2 phases/K-tile, 1 barrier/phase -------
#define MFMA_BF16 __builtin_amdgcn_mfma_f32_16x16x32_bf16
#define VM4 asm volatile("s_waitcnt vmcnt(4)" ::: "memory")
#define VM0 asm volatile("s_waitcnt vmcnt(0)" ::: "memory")
#define NOST ((void)0)

// Phase A: all 8 B-frags + A mf0-3 (16 ds_reads) | barrier | 32 MFMA.
#define PHA(BUF, STG, GATE)                                                     \
  do {                                                                          \
    _Pragma("unroll") for (int nf = 0; nf < 4; ++nf) {                          \
      bfrag[nf][0] = LDB(BUF, nf, 0);                                           \
      bfrag[nf][1] = LDB(BUF, nf, 1);                                           \
    }                                                                           \
    short8 af[4][2];                                                            \
    _Pragma("unroll") for (int m = 0; m < 4; ++m) {                             \
      af[m][0] = LDA(BUF, m, 0);                                                \
      af[m][1] = LDA(BUF, m, 1);                                                \
    }                                                                           \
    STG;                                                                        \
    GATE;                                                                       \
    __builtin_amdgcn_s_barrier();                                               \
    _Pragma("unroll") for (int kk = 0; kk < 2; ++kk)                            \
      _Pragma("unroll") for (int m = 0; m < 4; ++m)                             \
        _Pragma("unroll") for (int nf = 0; nf < 4; ++nf)                        \
          acc[m][nf] = MFMA_BF16(af[m][kk], bfrag[nf][kk], acc[m][nf], 0, 0, 0); \
  } while (0)

// Phase B: A mf4-7 (8 ds_reads) | barrier | 32 MFMA (bfrag reused).
#define PHB(BUF, STG, GATE)                                                     \
  do {                                                                          \
    short8 af[4][2];                                                            \
    _Pragma("unroll") for (int m = 0; m < 4; ++m) {                             \
      af[m][0] = LDA(BUF, m + 4, 0);                                            \
      af[m][1] = LDA(BUF, m + 4, 1);                                            \
    }                                                                           \
    STG;                                                                        \
    GATE;                                                                       \
    __builtin_amdgcn_s_barrier();                                               \
    _Pragma("unroll") for (int kk = 0; kk < 2; ++kk)                            \
      _Pragma("unroll") for (int m = 0; m < 4; ++m)                             \
        _Pragma("unroll") for (int nf = 0; nf < 4; ++nf)                        \
          acc[m + 4][nf] = MFMA_BF16(af[m][kk], bfrag[nf][kk], acc[m + 4][nf], 0, 0, 0); \
  } while (0)

template <int STORE_F32>
__global__ __launch_bounds__(512, 2) void k_gemm8(
    const bf16* __restrict__ A, const bf16* __restrict__ Bt,
    bf16* __restrict__ Cb, float* __restrict__ Cf, const float* __restrict__ bias) {
  __shared__ __align__(16) char smraw[131072];
  const int t = threadIdx.x;
  const int lane = t & 63;
  const int w = t >> 6;
  const int wr = w >> 2;
  const int wc = w & 3;

  const int bid = blockIdx.x;
  const int xcd = bid & 7;
  const int i = bid >> 3;
  const int bm = ((xcd >> 1) * 4 + (i & 3)) * 256;
  const int bn = ((xcd & 1) * 8 + (i >> 2)) * 256;

  f32x4 acc[8][4] = {};
  short8 bfrag[4][2];

  const int srow = w * 16 + (lane >> 3);
  const int sgr = lane & 7;

  // Stage both halves of A (or B) for K-tile kt into buf: 4 loads/thread.
  auto STAGE_A = [&](int buf, int kt) {
    #pragma unroll
    for (int half = 0; half < 2; ++half) {
      char* lb = smraw + buf * 65536 + half * 16384 + w * 2048 + lane * 16;
      #pragma unroll
      for (int i2 = 0; i2 < 2; ++i2) {
        int r = srow + i2 * 8;
        const bf16* g = A + (size_t)(bm + half * 128 + r) * 4096 + kt * 64 + ((sgr ^ (r & 7)) * 8);
        __builtin_amdgcn_global_load_lds(
            (const __attribute__((address_space(1))) void*)g,
            (__attribute__((address_space(3))) void*)(lb + i2 * 1024), 16, 0, 0);
      }
    }
  };
  auto STAGE_B = [&](int buf, int kt) {
    #pragma unroll
    for (int half = 0; half < 2; ++half) {
      char* lb = smraw + buf * 65536 + 32768 + half * 16384 + w * 2048 + lane * 16;
      #pragma unroll
      for (int i2 = 0; i2 < 2; ++i2) {
        int r = srow + i2 * 8;
        const bf16* g = Bt + (size_t)(bn + half * 128 + r) * 4096 + kt * 64 + ((sgr ^ (r & 7)) * 8);
        __builtin_amdgcn_global_load_lds(
            (const __attribute__((address_space(1))) void*)g,
            (__attribute__((address_space(3))) void*)(lb + i2 * 1024), 16, 0, 0);
      }
    }
  };
  auto LDA = [&](int buf, int mf, int kk) -> short8 {
    int r = mf * 16 + (lane & 15);
    int kb = ((kk * 4 + (lane >> 4)) ^ (r & 7)) * 16;
    return *reinterpret_cast<const short8*>(smraw + buf * 65536 + wr * 16384 + r * 128 + kb);
  };
  auto LDB = [&](int buf, int nf, int kk) -> short8 {
    int nc = wc * 64 + nf * 16 + (lane & 15);
    int half = nc >> 7, r = nc & 127;
    int kb = ((kk * 4 + (lane >> 4)) ^ (r & 7)) * 16;
    return *reinterpret_cast<const short8*>(smraw + buf * 65536 + 32768 + half * 16384 + r * 128 + kb);
  };

  // Prologue: B(0),A(0)->buf0; B(1)->buf1 (12 loads/thread... 12 total).
  // VM4 completes oldest 8 (B0,A0), leaves B(1)'s 4 in flight.
  STAGE_B(0, 0);
  STAGE_A(0, 0);
  STAGE_B(1, 1);
  VM4;
  __builtin_amdgcn_s_barrier();

  // Steady: tile a=2tt (buf0): PHA stages A(a+1)->buf1, PHB stages B(a+2)->buf0
  // + VM4 (completes A(a+1),B(a+1); leaves B(a+2)); tile a+1 (buf1) mirrored.
  for (int tt = 0; tt < 31; ++tt) {
    const int a = 2 * tt;
    PHA(0, STAGE_A(1, a + 1), NOST);
    PHB(0, STAGE_B(0, a + 2), VM4);
    PHA(1, STAGE_A(0, a + 2), NOST);
    PHB(1, STAGE_B(1, a + 3), VM4);
  }
  // Tail: tile 62 (buf0): PHA stages A(63)->buf1; PHB drains (VM0).
  // Tile 63 (buf1): compute only.
  PHA(0, STAGE_A(1, 63), NOST);
  PHB(0, NOST, VM0);
  PHA(1, NOST, NOST);
  PHB(1, NOST, NOST);

  const int cr = (lane >> 4) * 4;
  const int cc = lane & 15;
  #pragma unroll
  for (int mf = 0; mf < 8; ++mf) {
    #pragma unroll
    for (int nf = 0; nf < 4; ++nf) {
      int row = bm + wr * 128 + mf * 16 + cr;
      int col = bn + wc * 64 + nf * 16 + cc;
      #pragma unroll
      for (int r = 0; r < 4; ++r) {
        if constexpr (STORE_F32) {
          Cf[(size_t)(row + r) * 4096 + col] = acc[mf][nf][r] + bias[col];
        } else {
          Cb[(size_t)(row + r) * 4096 + col] = __float2bfloat16(acc[mf][nf][r]);
        }
      }
    }
  }
}

// ---- launch ----------------------------------------------------------------
extern "C" void kernel_launch(void* const* d_in, const int* in_sizes, int n_in,
                              void* d_out, int out_size, void* d_ws, size_t ws_size,
                              hipStream_t stream) {
  const float* x = (const float*)d_in[0];
  const float* gate_w = (const float*)d_in[1];
  const float* gate_b = (const float*)d_in[2];
  const float* weight = (const float*)d_in[3];
  const float* agg_w = (const float*)d_in[4];
  const float* agg_b = (const float*)d_in[5];
  float* out = (float*)d_out;
  char* ws = (char*)d_ws;

  // ws: colsum 16KB @0 | ids @16KB | mid 32MB @4MB | abt 32MB @36MB
  float* colsum = (float*)ws;
  int* ids = (int*)(ws + 16384);
  bf16* mid = (bf16*)(ws + (4u << 20));
  bf16* abt = (bf16*)(ws + (36u << 20));
  // scratch inside d_out (dead before GEMM2 writes it):
  bf16* xb = (bf16*)d_out;
  bf16* wbt = (bf16*)((char*)d_out + (32u << 20));

  hipMemsetAsync(colsum, 0, DIN * sizeof(float), stream);
  k_cvtsum<<<dim3(16, 32), 256, 0, stream>>>(x, xb, colsum);
  k_gate<<<1, 256, 0, stream>>>(colsum, gate_w, gate_b, ids);
  k_gather<<<2048, 256, 0, stream>>>(weight, agg_w, ids, wbt, abt);
  k_gemm8<0><<<256, 512, 0, stream>>>(xb, wbt, mid, nullptr, nullptr);
  k_gemm8<1><<<256, 512, 0, stream>>>(mid, abt, nullptr, out, agg_b);
}